// Round 11
// baseline (635.211 us; speedup 1.0000x reference)
//
#include <hip/hip_runtime.h>
#include <math.h>

#define NBLK  11
#define NAGG  4
#define NFILT 32
#define NPROP 20
#define BB    128
#define VV    1024
#define PARTS 4
#define PV    256     // vertices per WG
#define FIN   10
#define TPB   512
#define BN_EPS 1e-3f
#define SHS   40      // sH row stride in halves (80 B, 16B-aligned)

// d_ws floats: [0..127] int flags; mean[b][part][10] at WSF_MEAN; agg after.
#define WSF_MEAN 128
#define WSF_AGG  (WSF_MEAN + BB*PARTS*FIN)

typedef _Float16 f16;
typedef f16   f16x8 __attribute__((ext_vector_type(8)));
typedef float f32x4 __attribute__((ext_vector_type(4)));

__device__ __forceinline__ f32x4 MFMA(f16x8 a, f16x8 b, f32x4 c){
  return __builtin_amdgcn_mfma_f32_16x16x32_f16(a, b, c, 0, 0, 0);
}

__device__ __forceinline__ float fast_tanh(float x){
  float a = fabsf(x);
  float e = __expf(-2.0f * a);
  float r = (1.0f - e) / (1.0f + e);
  return copysignf(r, x);
}

// 4-way event sync: each of the 4 WGs posts once per round (RELEASE), spins
// (ACQUIRE) until all 4 posted. Parity double-buffer makes reuse race-free.
__device__ __forceinline__ void quad_sync(int* flag, int target){
  __syncthreads();
  if (threadIdx.x == 0){
    __hip_atomic_fetch_add(flag, 1, __ATOMIC_RELEASE, __HIP_MEMORY_SCOPE_AGENT);
    while (__hip_atomic_load(flag, __ATOMIC_ACQUIRE, __HIP_MEMORY_SCOPE_AGENT) < target)
      __builtin_amdgcn_s_sleep(2);
  }
  __syncthreads();
}

// __launch_bounds__(512, 4): min 4 waves/EU -> HARD VGPR cap 512/4 = 128.
// This makes 2 WGs/CU (16 waves, LDS 2x68=136<=160 KB) structurally guaranteed,
// which the quad_sync liveness REQUIRES (512 WGs all co-resident). r10 hung
// because without the cap the allocator exceeded 128 VGPR -> 1 WG/CU -> deadlock.
// Live set ~100 regs (acc[2][3]=24, stage2 2x12=24, frags transient) -> no spill.
// MFMA 16x16x32 frags (m89-verified): A[row=lane&15][k=8*(lane>>4)+j],
// B[k][col=lane&15], C[row=4*(lane>>4)+q][col=lane&15].
extern "C" __global__ __launch_bounds__(TPB, 4)
void garnet_fused(
    const float* __restrict__ x,
    const float* __restrict__ bn0_g, const float* __restrict__ bn0_b,
    const float* __restrict__ bn0_m, const float* __restrict__ bn0_v,
    const float* __restrict__ W_in,  const float* __restrict__ b_in,
    const float* __restrict__ W_flr, const float* __restrict__ b_flr,
    const float* __restrict__ W_s,   const float* __restrict__ b_s,
    const float* __restrict__ W_out, const float* __restrict__ b_out,
    const float* __restrict__ bn_g,  const float* __restrict__ bn_b,
    const float* __restrict__ bn_m,  const float* __restrict__ bn_v,
    const float* __restrict__ W_o0,  const float* __restrict__ b_o0,
    const float* __restrict__ W_o1,  const float* __restrict__ b_o1,
    int* __restrict__ wsFlag, float* __restrict__ wsF,
    float* __restrict__ out)
{
  const int wg   = blockIdx.x;
  const int b    = wg & (BB - 1);     // parts of event b at wg=b+128p -> same XCD (mod 8)
  const int part = wg >> 7;           // 0..3
  const int t    = threadIdx.x;
  const int lane = t & 63;
  const int wave = t >> 6;            // 0..7; wave owns rows [wave*32, wave*32+32)
  const int l16  = lane & 15;
  const int kb   = lane >> 4;

  __shared__ float sFeat[PV * 25];               // 25.6 KB fp32
  __shared__ __align__(16) f16 sHhi[PV * SHS];   // 20 KB
  __shared__ __align__(16) f16 sHlo[PV * SHS];   // 20 KB
  __shared__ f16   sMh[4 * 32];
  __shared__ float sAgg[NAGG][48];
  __shared__ float sRed[4][FIN];
  __shared__ float sMean[FIN];

  int* flag = wsFlag + b;

  // ---------------- phase 0: mean over V (4-way) + input dense (t<256) ----------------
  {
    float xv[FIN];
    if (t < PV){
      const float* xp = x + ((size_t)b * VV + part * PV + t) * FIN;
      #pragma unroll
      for (int c = 0; c < FIN; ++c) xv[c] = xp[c];
    } else {
      #pragma unroll
      for (int c = 0; c < FIN; ++c) xv[c] = 0.f;
    }
    float ps[FIN];
    #pragma unroll
    for (int c = 0; c < FIN; ++c) ps[c] = xv[c];
    #pragma unroll
    for (int m = 32; m > 0; m >>= 1){
      #pragma unroll
      for (int c = 0; c < FIN; ++c) ps[c] += __shfl_xor(ps[c], m, 64);
    }
    if (lane == 0 && wave < 4){
      #pragma unroll
      for (int c = 0; c < FIN; ++c) sRed[wave][c] = ps[c];
    }
    __syncthreads();
    if (t < FIN){
      float s = 0.f;
      #pragma unroll
      for (int wv = 0; wv < 4; ++wv) s += sRed[wv][t];
      __hip_atomic_store(&wsF[WSF_MEAN + (b*PARTS + part)*FIN + t], s,
                         __ATOMIC_RELAXED, __HIP_MEMORY_SCOPE_AGENT);
    }
    quad_sync(flag, PARTS);
    if (t < FIN){
      float s = 0.f;
      #pragma unroll
      for (int p = 0; p < PARTS; ++p)
        s += __hip_atomic_load(&wsF[WSF_MEAN + (b*PARTS + p)*FIN + t],
                               __ATOMIC_RELAXED, __HIP_MEMORY_SCOPE_AGENT);
      sMean[t] = s * (1.0f / VV);
    }
    __syncthreads();

    if (t < PV){
      float o[NFILT];
      #pragma unroll
      for (int j = 0; j < NFILT; ++j) o[j] = b_in[j];
      #pragma unroll
      for (int c = 0; c < FIN; ++c){
        const float zx = (xv[c]     - bn0_m[c])     * (bn0_g[c]     * rsqrtf(bn0_v[c]     + BN_EPS)) + bn0_b[c];
        const float zm = (sMean[c]  - bn0_m[FIN+c]) * (bn0_g[FIN+c] * rsqrtf(bn0_v[FIN+c] + BN_EPS)) + bn0_b[FIN+c];
        #pragma unroll
        for (int j = 0; j < NFILT; ++j)
          o[j] += zx * W_in[c*NFILT + j] + zm * W_in[(FIN+c)*NFILT + j];
      }
      #pragma unroll
      for (int cc = 0; cc < 4; ++cc){
        f16x8 hh, hl;
        #pragma unroll
        for (int j = 0; j < 8; ++j){
          const float hv = fast_tanh(o[cc*8 + j]);
          const f16 a = (f16)hv;
          hh[j] = a;
          hl[j] = (f16)(hv - (float)a);
        }
        *(f16x8*)&sHhi[t*SHS + cc*8] = hh;
        *(f16x8*)&sHlo[t*SHS + cc*8] = hl;
      }
    }
  }
  __syncthreads();

  // head accumulator as MFMA C-frags: acc[tile][colblk], col = s*16+l16
  f32x4 acc[2][3];
  #pragma unroll
  for (int s = 0; s < 3; ++s){
    const float a0 = b_o0[s*16 + l16];
    #pragma unroll
    for (int i = 0; i < 2; ++i) acc[i][s] = (f32x4){a0, a0, a0, a0};
  }

  for (int l = 0; l < NBLK; ++l){
    const float* Wf = W_flr + l * NFILT * NPROP;
    const float* bf = b_flr + l * NPROP;
    const float* Ws = W_s   + l * NFILT * NAGG;
    const float* bs = b_s   + l * NAGG;
    const float* Wo = W_out + l * 228 * NFILT;
    const float* bo = b_out + l * NFILT;
    const float* g_ = bn_g  + l * NFILT;
    const float* be = bn_b  + l * NFILT;
    const float* bm = bn_m  + l * NFILT;
    const float* bv = bn_v  + l * NFILT;

    // ---- stage 1 (MFMA): feat = h @ [Wf|Ws], w = exp(-|d|) -> sFeat fp32 ----
    {
      f16x8 b1f[2];
      #pragma unroll
      for (int s = 0; s < 2; ++s){
        #pragma unroll
        for (int j = 0; j < 8; ++j){
          const int k = kb*8 + j, n = s*16 + l16;
          float val;
          if (s == 0) val = Wf[k*NPROP + n];
          else        val = (n < 20) ? Wf[k*NPROP + n] : (n < 24 ? Ws[k*NAGG + (n-20)] : 0.f);
          b1f[s][j] = (f16)val;
        }
      }
      const float bias0 = bf[l16];
      const int  c1 = 16 + l16;
      const float bias1 = (c1 < 20) ? bf[c1] : (c1 < 24 ? bs[c1-20] : 0.f);

      #pragma unroll
      for (int i = 0; i < 2; ++i){
        const int tb = wave*32 + i*16;
        const f16x8 ahi = *(const f16x8*)&sHhi[(tb + l16)*SHS + kb*8];
        const f16x8 alo = *(const f16x8*)&sHlo[(tb + l16)*SHS + kb*8];
        f32x4 c0 = (f32x4){bias0, bias0, bias0, bias0};
        c0 = MFMA(ahi, b1f[0], c0);
        c0 = MFMA(alo, b1f[0], c0);
        #pragma unroll
        for (int q = 0; q < 4; ++q)
          sFeat[(tb + kb*4 + q)*25 + l16] = c0[q];
        f32x4 c1v = (f32x4){bias1, bias1, bias1, bias1};
        c1v = MFMA(ahi, b1f[1], c1v);
        c1v = MFMA(alo, b1f[1], c1v);
        if (l16 < 4){
          #pragma unroll
          for (int q = 0; q < 4; ++q)
            sFeat[(tb + kb*4 + q)*25 + 16 + l16] = c1v[q];
        } else if (l16 < 8){
          #pragma unroll
          for (int q = 0; q < 4; ++q)
            sFeat[(tb + kb*4 + q)*25 + 16 + l16] = __expf(-fabsf(c1v[q]));
        }
      }
    }
    __syncthreads();

    // ---- stage 2: partial max/sum over 256 rows; wave owns 3 cols ----
    {
      const int w3 = wave * 3;
      float psum[NAGG][3], pmax[NAGG][3];
      #pragma unroll
      for (int a = 0; a < NAGG; ++a)
        #pragma unroll
        for (int c = 0; c < 3; ++c){ psum[a][c] = 0.f; pmax[a][c] = -INFINITY; }
      #pragma unroll
      for (int i = 0; i < 4; ++i){
        const int row = i * 64 + lane;
        float fc[3], wa[NAGG];
        #pragma unroll
        for (int c = 0; c < 3; ++c) fc[c] = sFeat[row*25 + w3 + c];
        #pragma unroll
        for (int a = 0; a < NAGG; ++a) wa[a] = sFeat[row*25 + NPROP + a];
        #pragma unroll
        for (int a = 0; a < NAGG; ++a)
          #pragma unroll
          for (int c = 0; c < 3; ++c){
            const float p = wa[a] * fc[c];
            psum[a][c] += p;
            pmax[a][c]  = fmaxf(pmax[a][c], p);
          }
      }
      #pragma unroll
      for (int m = 32; m > 0; m >>= 1){
        #pragma unroll
        for (int a = 0; a < NAGG; ++a)
          #pragma unroll
          for (int c = 0; c < 3; ++c){
            psum[a][c] += __shfl_xor(psum[a][c], m, 64);
            pmax[a][c]  = fmaxf(pmax[a][c], __shfl_xor(pmax[a][c], m, 64));
          }
      }
      if (lane == 0){
        float* gp = wsF + WSF_AGG + (((size_t)(b*2 + (l&1))*PARTS + part) * NAGG * 48);
        #pragma unroll
        for (int a = 0; a < NAGG; ++a)
          #pragma unroll
          for (int c = 0; c < 3; ++c){
            __hip_atomic_store(&gp[a*48 + w3 + c],      pmax[a][c], __ATOMIC_RELAXED, __HIP_MEMORY_SCOPE_AGENT);
            __hip_atomic_store(&gp[a*48 + 24 + w3 + c], psum[a][c], __ATOMIC_RELAXED, __HIP_MEMORY_SCOPE_AGENT);
          }
      }
    }
    quad_sync(flag, 4*l + 8);

    // ---- combine 4 parts: max of maxes, mean = sum/V ----
    if (t < 192){
      const int a = t / 48, c = t - a * 48;
      const size_t base = WSF_AGG + ((size_t)(b*2 + (l&1))*PARTS) * NAGG * 48;
      float v0 = __hip_atomic_load(&wsF[base + (size_t)(0*NAGG*48) + a*48 + c], __ATOMIC_RELAXED, __HIP_MEMORY_SCOPE_AGENT);
      float v1 = __hip_atomic_load(&wsF[base + (size_t)(1*NAGG*48) + a*48 + c], __ATOMIC_RELAXED, __HIP_MEMORY_SCOPE_AGENT);
      float v2 = __hip_atomic_load(&wsF[base + (size_t)(2*NAGG*48) + a*48 + c], __ATOMIC_RELAXED, __HIP_MEMORY_SCOPE_AGENT);
      float v3 = __hip_atomic_load(&wsF[base + (size_t)(3*NAGG*48) + a*48 + c], __ATOMIC_RELAXED, __HIP_MEMORY_SCOPE_AGENT);
      sAgg[a][c] = (c < 24) ? fmaxf(fmaxf(v0, v1), fmaxf(v2, v3))
                            : (v0 + v1 + v2 + v3) * (1.0f / VV);
    }
    __syncthreads();

    // ---- M'[a][j] -> fp16 ----
    if (t < 128){
      const int a = t >> 5, j = t & 31;
      float m = Wo[(224 + a) * NFILT + j];
      #pragma unroll 8
      for (int c = 0; c < 48; ++c) m += sAgg[a][c] * Wo[(32 + a*48 + c) * NFILT + j];
      sMh[a*32 + j] = (f16)m;
    }
    __syncthreads();

    // ---- stage 3 (MFMA): o = h@WoH + w@M' + bo; h_new = bn(tanh(o)) -> sH ----
    {
      f16x8 b2f[2], bmf[2];
      #pragma unroll
      for (int s = 0; s < 2; ++s){
        #pragma unroll
        for (int j = 0; j < 8; ++j){
          const int k = kb*8 + j;
          b2f[s][j] = (f16)Wo[k*NFILT + s*16 + l16];
          bmf[s][j] = (kb == 0 && j < 4) ? sMh[j*32 + s*16 + l16] : (f16)0.f;
        }
      }
      float boc[2], bmc[2], scc[2], bec[2];
      #pragma unroll
      for (int s = 0; s < 2; ++s){
        const int cc = s*16 + l16;
        boc[s] = bo[cc];
        bmc[s] = bm[cc];
        scc[s] = g_[cc] * rsqrtf(bv[cc] + BN_EPS);
        bec[s] = be[cc];
      }

      #pragma unroll
      for (int i = 0; i < 2; ++i){
        const int tb = wave*32 + i*16;
        const f16x8 ahi = *(const f16x8*)&sHhi[(tb + l16)*SHS + kb*8];
        const f16x8 alo = *(const f16x8*)&sHlo[(tb + l16)*SHS + kb*8];
        f16x8 wa;
        #pragma unroll
        for (int j = 0; j < 8; ++j) wa[j] = (f16)0.f;
        {
          const float w0 = sFeat[(tb + l16)*25 + 20];
          const float w1 = sFeat[(tb + l16)*25 + 21];
          const float w2 = sFeat[(tb + l16)*25 + 22];
          const float w3 = sFeat[(tb + l16)*25 + 23];
          if (kb == 0){ wa[0]=(f16)w0; wa[1]=(f16)w1; wa[2]=(f16)w2; wa[3]=(f16)w3; }
        }
        #pragma unroll
        for (int s = 0; s < 2; ++s){
          f32x4 o = (f32x4){0.f, 0.f, 0.f, 0.f};
          o = MFMA(ahi, b2f[s], o);
          o = MFMA(alo, b2f[s], o);
          o = MFMA(wa,  bmf[s], o);
          #pragma unroll
          for (int q = 0; q < 4; ++q){
            const float th = fast_tanh(o[q] + boc[s]);
            const float hn = (th - bmc[s]) * scc[s] + bec[s];
            const f16 hh = (f16)hn;
            const int idx = (tb + kb*4 + q)*SHS + s*16 + l16;
            sHhi[idx] = hh;
            sHlo[idx] = (f16)(hn - (float)hh);
          }
        }
      }
    }
    // stage3 writes and phaseC reads touch the same wave-owned 16-row tiles:
    // same-wave LDS RAW is safe after the wave's own ds ops drain.
    asm volatile("s_waitcnt lgkmcnt(0)" ::: "memory");

    // ---- phase C (MFMA): acc += h_new @ W_o0_slice ----
    {
      const float* Wo0l = W_o0 + (size_t)l * NFILT * 48;
      f16x8 b3f[3];
      #pragma unroll
      for (int s = 0; s < 3; ++s)
        #pragma unroll
        for (int j = 0; j < 8; ++j)
          b3f[s][j] = (f16)Wo0l[(kb*8 + j)*48 + s*16 + l16];
      #pragma unroll
      for (int i = 0; i < 2; ++i){
        const int tb = wave*32 + i*16;
        const f16x8 ahi = *(const f16x8*)&sHhi[(tb + l16)*SHS + kb*8];
        const f16x8 alo = *(const f16x8*)&sHlo[(tb + l16)*SHS + kb*8];
        #pragma unroll
        for (int s = 0; s < 3; ++s){
          acc[i][s] = MFMA(ahi, b3f[s], acc[i][s]);
          acc[i][s] = MFMA(alo, b3f[s], acc[i][s]);
        }
      }
    }
  }

  // ---------------- head: out = relu(relu(acc) @ W_o1 + b_o1) ----------------
  {
    float w1c[3][3];
    #pragma unroll
    for (int s = 0; s < 3; ++s)
      #pragma unroll
      for (int m = 0; m < 3; ++m) w1c[s][m] = W_o1[(s*16 + l16)*3 + m];
    const float bo1_0 = b_o1[0], bo1_1 = b_o1[1], bo1_2 = b_o1[2];

    #pragma unroll
    for (int i = 0; i < 2; ++i){
      const int tb = wave*32 + i*16;
      float p[4][3];
      #pragma unroll
      for (int q = 0; q < 4; ++q){ p[q][0]=0.f; p[q][1]=0.f; p[q][2]=0.f; }
      #pragma unroll
      for (int s = 0; s < 3; ++s)
        #pragma unroll
        for (int q = 0; q < 4; ++q){
          const float r_ = fmaxf(acc[i][s][q], 0.f);
          p[q][0] += r_ * w1c[s][0];
          p[q][1] += r_ * w1c[s][1];
          p[q][2] += r_ * w1c[s][2];
        }
      #pragma unroll
      for (int m = 1; m <= 8; m <<= 1)
        #pragma unroll
        for (int q = 0; q < 4; ++q){
          p[q][0] += __shfl_xor(p[q][0], m, 64);
          p[q][1] += __shfl_xor(p[q][1], m, 64);
          p[q][2] += __shfl_xor(p[q][2], m, 64);
        }
      if (l16 < 3){
        const float bo1v = (l16 == 0) ? bo1_0 : ((l16 == 1) ? bo1_1 : bo1_2);
        #pragma unroll
        for (int q = 0; q < 4; ++q){
          const float vv = (l16 == 0) ? p[q][0] : ((l16 == 1) ? p[q][1] : p[q][2]);
          out[((size_t)b*VV + part*PV + tb + kb*4 + q)*3 + l16] = fmaxf(vv + bo1v, 0.f);
        }
      }
    }
  }
}

extern "C" void kernel_launch(void* const* d_in, const int* in_sizes, int n_in,
                              void* d_out, int out_size, void* d_ws, size_t ws_size,
                              hipStream_t stream) {
  const float* x      = (const float*)d_in[0];
  const float* bn0_g  = (const float*)d_in[1];
  const float* bn0_b  = (const float*)d_in[2];
  const float* bn0_m  = (const float*)d_in[3];
  const float* bn0_v  = (const float*)d_in[4];
  const float* W_in   = (const float*)d_in[5];
  const float* b_in   = (const float*)d_in[6];
  const float* W_flr  = (const float*)d_in[7];
  const float* b_flr  = (const float*)d_in[8];
  const float* W_s    = (const float*)d_in[9];
  const float* b_s    = (const float*)d_in[10];
  const float* W_out  = (const float*)d_in[11];
  const float* b_out  = (const float*)d_in[12];
  const float* bn_g   = (const float*)d_in[13];
  const float* bn_b   = (const float*)d_in[14];
  const float* bn_m   = (const float*)d_in[15];
  const float* bn_v   = (const float*)d_in[16];
  const float* W_o0   = (const float*)d_in[17];
  const float* b_o0   = (const float*)d_in[18];
  const float* W_o1   = (const float*)d_in[19];
  const float* b_o1   = (const float*)d_in[20];

  hipMemsetAsync(d_ws, 0, BB * sizeof(int), stream);

  garnet_fused<<<dim3(BB * PARTS), dim3(TPB), 0, stream>>>(
      x, bn0_g, bn0_b, bn0_m, bn0_v, W_in, b_in,
      W_flr, b_flr, W_s, b_s, W_out, b_out,
      bn_g, bn_b, bn_m, bn_v, W_o0, b_o0, W_o1, b_o1,
      (int*)d_ws, (float*)d_ws, (float*)d_out);
}

// Round 13
// 184.165 us; speedup vs baseline: 3.4491x; 3.4491x over previous
//
#include <hip/hip_runtime.h>
#include <math.h>

#define NBLK  11
#define NAGG  4
#define NFILT 32
#define NPROP 20
#define BB    128
#define VV    1024
#define HV    512
#define FIN   10
#define TPB   512
#define BN_EPS 1e-3f
#define SHS   40   // sH row stride in halves: 80 B = 16B-aligned

#define WSF_MEAN 128
#define WSF_AGG  (WSF_MEAN + BB*2*FIN)

typedef _Float16 f16;
typedef f16   f16x8 __attribute__((ext_vector_type(8)));
typedef float f32x4 __attribute__((ext_vector_type(4)));

__device__ __forceinline__ f32x4 MFMA(f16x8 a, f16x8 b, f32x4 c){
  return __builtin_amdgcn_mfma_f32_16x16x32_f16(a, b, c, 0, 0, 0);
}

__device__ __forceinline__ float fast_tanh(float x){
  float a = fabsf(x);
  float e = __expf(-2.0f * a);
  float r = (1.0f - e) / (1.0f + e);
  return copysignf(r, x);
}

// Pairwise event sync, RELAXED version (no wbl2 flush):
// All cross-WG data are agent-scope ATOMICS (individually coherent); the only
// ordering needed is data-stores-complete-before-flag-bump. __syncthreads
// drains every wave's vmcnt before the barrier, so by the time thread 0 runs,
// all waves' data stores have completed at the coherence point. The explicit
// vmcnt(0) is belt-and-braces for wave 0's own stores. No RELEASE -> no
// buffer_wbl2 L2 flush (which cost ~MBs of writeback x 12 rounds in r8).
__device__ __forceinline__ void pair_sync(int* flag, int target){
  __syncthreads();
  if (threadIdx.x == 0){
    asm volatile("s_waitcnt vmcnt(0)" ::: "memory");
    __hip_atomic_fetch_add(flag, 1, __ATOMIC_RELAXED, __HIP_MEMORY_SCOPE_AGENT);
    while (__hip_atomic_load(flag, __ATOMIC_RELAXED, __HIP_MEMORY_SCOPE_AGENT) < target)
      __builtin_amdgcn_s_sleep(2);
  }
  __syncthreads();
}

// r8 structure (proven 244us): 256 WGs, 2 per event, 1 WG/CU (LDS ~134 KB),
// co-residency trivially safe (256 WGs <= 256 CUs). TPB=512 -> 128 VGPR.
// MFMA 16x16x32 frags (m89-verified): A[row=lane&15][k=8*(lane>>4)+j],
// B[k][col=lane&15], C[row=4*(lane>>4)+q][col=lane&15].
extern "C" __global__ __launch_bounds__(TPB)
void garnet_fused(
    const float* __restrict__ x,
    const float* __restrict__ bn0_g, const float* __restrict__ bn0_b,
    const float* __restrict__ bn0_m, const float* __restrict__ bn0_v,
    const float* __restrict__ W_in,  const float* __restrict__ b_in,
    const float* __restrict__ W_flr, const float* __restrict__ b_flr,
    const float* __restrict__ W_s,   const float* __restrict__ b_s,
    const float* __restrict__ W_out, const float* __restrict__ b_out,
    const float* __restrict__ bn_g,  const float* __restrict__ bn_b,
    const float* __restrict__ bn_m,  const float* __restrict__ bn_v,
    const float* __restrict__ W_o0,  const float* __restrict__ b_o0,
    const float* __restrict__ W_o1,  const float* __restrict__ b_o1,
    int* __restrict__ wsFlag, float* __restrict__ wsF,
    float* __restrict__ out)
{
  const int wg   = blockIdx.x;
  const int b    = wg & (BB - 1);
  const int half = wg >> 7;
  const int t    = threadIdx.x;
  const int lane = t & 63;
  const int wave = t >> 6;
  const int v    = half * HV + t;
  const int l16  = lane & 15;
  const int kb   = lane >> 4;

  __shared__ float sFeat[HV * 25];                 // 50 KB fp32
  __shared__ __align__(16) f16 sHhi[HV * SHS];     // 40 KB
  __shared__ __align__(16) f16 sHlo[HV * SHS];     // 40 KB
  __shared__ f16   sMh[4 * 32];
  __shared__ float sAgg[NAGG][48];
  __shared__ float sRed[8][FIN];
  __shared__ float sMean[FIN];

  int* flag = wsFlag + b;

  // ---------------- phase 0: mean over V (cross-half) + input dense ----------------
  {
    float h[NFILT];
    float xv[FIN];
    const float* xp = x + ((size_t)b * VV + v) * FIN;
    #pragma unroll
    for (int c = 0; c < FIN; ++c) xv[c] = xp[c];

    float ps[FIN];
    #pragma unroll
    for (int c = 0; c < FIN; ++c) ps[c] = xv[c];
    #pragma unroll
    for (int m = 32; m > 0; m >>= 1){
      #pragma unroll
      for (int c = 0; c < FIN; ++c) ps[c] += __shfl_xor(ps[c], m, 64);
    }
    if (lane == 0){
      #pragma unroll
      for (int c = 0; c < FIN; ++c) sRed[wave][c] = ps[c];
    }
    __syncthreads();
    if (t < FIN){
      float s = 0.f;
      #pragma unroll
      for (int wv = 0; wv < 8; ++wv) s += sRed[wv][t];
      sRed[0][t] = s;
      __hip_atomic_store(&wsF[WSF_MEAN + (b*2 + half)*FIN + t], s,
                         __ATOMIC_RELAXED, __HIP_MEMORY_SCOPE_AGENT);
    }
    pair_sync(flag, 2);
    if (t < FIN){
      float theirs = __hip_atomic_load(&wsF[WSF_MEAN + (b*2 + (half^1))*FIN + t],
                                       __ATOMIC_RELAXED, __HIP_MEMORY_SCOPE_AGENT);
      sMean[t] = (sRed[0][t] + theirs) * (1.0f / VV);
    }
    __syncthreads();

    float o[NFILT];
    #pragma unroll
    for (int j = 0; j < NFILT; ++j) o[j] = b_in[j];
    #pragma unroll
    for (int c = 0; c < FIN; ++c){
      const float zx = (xv[c]    - bn0_m[c])     * (bn0_g[c]     * rsqrtf(bn0_v[c]     + BN_EPS)) + bn0_b[c];
      const float zm = (sMean[c] - bn0_m[FIN+c]) * (bn0_g[FIN+c] * rsqrtf(bn0_v[FIN+c] + BN_EPS)) + bn0_b[FIN+c];
      #pragma unroll
      for (int j = 0; j < NFILT; ++j)
        o[j] += zx * W_in[c*NFILT + j] + zm * W_in[(FIN+c)*NFILT + j];
    }
    #pragma unroll
    for (int j = 0; j < NFILT; ++j) h[j] = fast_tanh(o[j]);

    #pragma unroll
    for (int c = 0; c < 4; ++c){
      f16x8 hh, hl;
      #pragma unroll
      for (int j = 0; j < 8; ++j){
        const float hv = h[c*8 + j];
        const f16 a = (f16)hv;
        hh[j] = a;
        hl[j] = (f16)(hv - (float)a);
      }
      *(f16x8*)&sHhi[t*SHS + c*8] = hh;
      *(f16x8*)&sHlo[t*SHS + c*8] = hl;
    }
  }
  __syncthreads();

  // head accumulator as MFMA C-frags: acc[tile][colblk], col = s*16+l16
  f32x4 acc[4][3];
  #pragma unroll
  for (int s = 0; s < 3; ++s){
    const float a0 = b_o0[s*16 + l16];
    #pragma unroll
    for (int i = 0; i < 4; ++i) acc[i][s] = (f32x4){a0, a0, a0, a0};
  }

  for (int l = 0; l < NBLK; ++l){
    const float* Wf = W_flr + l * NFILT * NPROP;
    const float* bf = b_flr + l * NPROP;
    const float* Ws = W_s   + l * NFILT * NAGG;
    const float* bs = b_s   + l * NAGG;
    const float* Wo = W_out + l * 228 * NFILT;
    const float* bo = b_out + l * NFILT;
    const float* g_ = bn_g  + l * NFILT;
    const float* be = bn_b  + l * NFILT;
    const float* bm = bn_m  + l * NFILT;
    const float* bv = bn_v  + l * NFILT;

    // ---- stage 1 (MFMA): feat = h @ [Wf|Ws], w = exp(-|d|) -> sFeat fp32 ----
    {
      f16x8 b1f[2];
      #pragma unroll
      for (int s = 0; s < 2; ++s){
        #pragma unroll
        for (int j = 0; j < 8; ++j){
          const int k = kb*8 + j, n = s*16 + l16;
          float val;
          if (s == 0) val = Wf[k*NPROP + n];
          else        val = (n < 20) ? Wf[k*NPROP + n] : (n < 24 ? Ws[k*NAGG + (n-20)] : 0.f);
          b1f[s][j] = (f16)val;
        }
      }
      const float bias0 = bf[l16];
      const int  c1 = 16 + l16;
      const float bias1 = (c1 < 20) ? bf[c1] : (c1 < 24 ? bs[c1-20] : 0.f);

      #pragma unroll
      for (int i = 0; i < 4; ++i){
        const int tb = wave*64 + i*16;
        const f16x8 ahi = *(const f16x8*)&sHhi[(tb + l16)*SHS + kb*8];
        const f16x8 alo = *(const f16x8*)&sHlo[(tb + l16)*SHS + kb*8];
        f32x4 c0 = (f32x4){bias0, bias0, bias0, bias0};
        c0 = MFMA(ahi, b1f[0], c0);
        c0 = MFMA(alo, b1f[0], c0);
        #pragma unroll
        for (int q = 0; q < 4; ++q)
          sFeat[(tb + kb*4 + q)*25 + l16] = c0[q];
        f32x4 c1v = (f32x4){bias1, bias1, bias1, bias1};
        c1v = MFMA(ahi, b1f[1], c1v);
        c1v = MFMA(alo, b1f[1], c1v);
        if (l16 < 4){
          #pragma unroll
          for (int q = 0; q < 4; ++q)
            sFeat[(tb + kb*4 + q)*25 + 16 + l16] = c1v[q];
        } else if (l16 < 8){
          #pragma unroll
          for (int q = 0; q < 4; ++q)
            sFeat[(tb + kb*4 + q)*25 + 16 + l16] = __expf(-fabsf(c1v[q]));
        }
      }
    }
    __syncthreads();

    // ---- stage 2: partial max/sum over 512 rows; wave owns cols 3w..3w+2 ----
    // 8 waves x 3 cols = 24 cols; 24 acc regs/thread (was 6 waves x 32 regs).
    {
      const int w3 = wave * 3;
      float psum[NAGG][3], pmax[NAGG][3];
      #pragma unroll
      for (int a = 0; a < NAGG; ++a)
        #pragma unroll
        for (int c = 0; c < 3; ++c){ psum[a][c] = 0.f; pmax[a][c] = -INFINITY; }
      for (int i = 0; i < 8; ++i){
        const int row = i * 64 + lane;
        float fc[3], wa[NAGG];
        #pragma unroll
        for (int c = 0; c < 3; ++c) fc[c] = sFeat[row*25 + w3 + c];
        #pragma unroll
        for (int a = 0; a < NAGG; ++a) wa[a] = sFeat[row*25 + NPROP + a];
        #pragma unroll
        for (int a = 0; a < NAGG; ++a)
          #pragma unroll
          for (int c = 0; c < 3; ++c){
            const float p = wa[a] * fc[c];
            psum[a][c] += p;
            pmax[a][c]  = fmaxf(pmax[a][c], p);
          }
      }
      #pragma unroll
      for (int m = 32; m > 0; m >>= 1){
        #pragma unroll
        for (int a = 0; a < NAGG; ++a)
          #pragma unroll
          for (int c = 0; c < 3; ++c){
            psum[a][c] += __shfl_xor(psum[a][c], m, 64);
            pmax[a][c]  = fmaxf(pmax[a][c], __shfl_xor(pmax[a][c], m, 64));
          }
      }
      if (lane == 0){
        float* gp = wsF + WSF_AGG + (((size_t)(b*2 + (l&1))*2 + half) * NAGG * 48);
        #pragma unroll
        for (int a = 0; a < NAGG; ++a)
          #pragma unroll
          for (int c = 0; c < 3; ++c){
            sAgg[a][w3 + c]      = pmax[a][c];
            sAgg[a][24 + w3 + c] = psum[a][c];
            __hip_atomic_store(&gp[a*48 + w3 + c],      pmax[a][c], __ATOMIC_RELAXED, __HIP_MEMORY_SCOPE_AGENT);
            __hip_atomic_store(&gp[a*48 + 24 + w3 + c], psum[a][c], __ATOMIC_RELAXED, __HIP_MEMORY_SCOPE_AGENT);
          }
      }
    }
    pair_sync(flag, 2*l + 4);

    if (t < 192){
      const int a = t / 48, c = t - a * 48;
      const float* pp = wsF + WSF_AGG + (((size_t)(b*2 + (l&1))*2 + (half^1)) * NAGG * 48);
      const float mine   = sAgg[a][c];
      const float theirs = __hip_atomic_load(&pp[a*48 + c], __ATOMIC_RELAXED, __HIP_MEMORY_SCOPE_AGENT);
      sAgg[a][c] = (c < 24) ? fmaxf(mine, theirs) : (mine + theirs) * (1.0f / VV);
    }
    __syncthreads();

    // ---- M'[a][j] -> fp16 (B-frag source for w@M') ----
    if (t < 128){
      const int a = t >> 5, j = t & 31;
      float m = Wo[(224 + a) * NFILT + j];
      #pragma unroll 8
      for (int c = 0; c < 48; ++c) m += sAgg[a][c] * Wo[(32 + a*48 + c) * NFILT + j];
      sMh[a*32 + j] = (f16)m;
    }
    __syncthreads();

    // ---- stage 3 (MFMA): o = h@WoH + w@M' + bo; h_new = bn(tanh(o)) -> sH ----
    {
      f16x8 b2f[2], bmf[2];
      #pragma unroll
      for (int s = 0; s < 2; ++s){
        #pragma unroll
        for (int j = 0; j < 8; ++j){
          const int k = kb*8 + j;
          b2f[s][j] = (f16)Wo[k*NFILT + s*16 + l16];
          bmf[s][j] = (kb == 0 && j < 4) ? sMh[j*32 + s*16 + l16] : (f16)0.f;
        }
      }
      float boc[2], bmc[2], scc[2], bec[2];
      #pragma unroll
      for (int s = 0; s < 2; ++s){
        const int cc = s*16 + l16;
        boc[s] = bo[cc];
        bmc[s] = bm[cc];
        scc[s] = g_[cc] * rsqrtf(bv[cc] + BN_EPS);
        bec[s] = be[cc];
      }

      #pragma unroll
      for (int i = 0; i < 4; ++i){
        const int tb = wave*64 + i*16;
        const f16x8 ahi = *(const f16x8*)&sHhi[(tb + l16)*SHS + kb*8];
        const f16x8 alo = *(const f16x8*)&sHlo[(tb + l16)*SHS + kb*8];
        f16x8 wa;
        #pragma unroll
        for (int j = 0; j < 8; ++j) wa[j] = (f16)0.f;
        {
          const float w0 = sFeat[(tb + l16)*25 + 20];
          const float w1 = sFeat[(tb + l16)*25 + 21];
          const float w2 = sFeat[(tb + l16)*25 + 22];
          const float w3v = sFeat[(tb + l16)*25 + 23];
          if (kb == 0){ wa[0]=(f16)w0; wa[1]=(f16)w1; wa[2]=(f16)w2; wa[3]=(f16)w3v; }
        }
        #pragma unroll
        for (int s = 0; s < 2; ++s){
          f32x4 o = (f32x4){0.f, 0.f, 0.f, 0.f};
          o = MFMA(ahi, b2f[s], o);
          o = MFMA(alo, b2f[s], o);
          o = MFMA(wa,  bmf[s], o);
          #pragma unroll
          for (int q = 0; q < 4; ++q){
            const float th = fast_tanh(o[q] + boc[s]);
            const float hn = (th - bmc[s]) * scc[s] + bec[s];
            const f16 hh = (f16)hn;
            const int idx = (tb + kb*4 + q)*SHS + s*16 + l16;
            sHhi[idx] = hh;
            sHlo[idx] = (f16)(hn - (float)hh);
          }
        }
      }
    }
    // stage3 writes and phaseC reads touch the same wave-owned 16-row tiles:
    // same-wave LDS RAW is safe once this wave's own ds ops drain.
    asm volatile("s_waitcnt lgkmcnt(0)" ::: "memory");

    // ---- phase C (MFMA): acc += h_new @ W_o0_slice ----
    {
      const float* Wo0l = W_o0 + (size_t)l * NFILT * 48;
      f16x8 b3f[3];
      #pragma unroll
      for (int s = 0; s < 3; ++s)
        #pragma unroll
        for (int j = 0; j < 8; ++j)
          b3f[s][j] = (f16)Wo0l[(kb*8 + j)*48 + s*16 + l16];
      #pragma unroll
      for (int i = 0; i < 4; ++i){
        const int tb = wave*64 + i*16;
        const f16x8 ahi = *(const f16x8*)&sHhi[(tb + l16)*SHS + kb*8];
        const f16x8 alo = *(const f16x8*)&sHlo[(tb + l16)*SHS + kb*8];
        #pragma unroll
        for (int s = 0; s < 3; ++s){
          acc[i][s] = MFMA(ahi, b3f[s], acc[i][s]);
          acc[i][s] = MFMA(alo, b3f[s], acc[i][s]);
        }
      }
    }
  }

  // ---------------- head: out = relu(relu(acc) @ W_o1 + b_o1), from C-frags ----------------
  {
    float w1c[3][3];
    #pragma unroll
    for (int s = 0; s < 3; ++s)
      #pragma unroll
      for (int m = 0; m < 3; ++m) w1c[s][m] = W_o1[(s*16 + l16)*3 + m];
    const float bo1_0 = b_o1[0], bo1_1 = b_o1[1], bo1_2 = b_o1[2];

    #pragma unroll
    for (int i = 0; i < 4; ++i){
      const int tb = wave*64 + i*16;
      float p[4][3];
      #pragma unroll
      for (int q = 0; q < 4; ++q){ p[q][0]=0.f; p[q][1]=0.f; p[q][2]=0.f; }
      #pragma unroll
      for (int s = 0; s < 3; ++s)
        #pragma unroll
        for (int q = 0; q < 4; ++q){
          const float r_ = fmaxf(acc[i][s][q], 0.f);
          p[q][0] += r_ * w1c[s][0];
          p[q][1] += r_ * w1c[s][1];
          p[q][2] += r_ * w1c[s][2];
        }
      #pragma unroll
      for (int m = 1; m <= 8; m <<= 1)
        #pragma unroll
        for (int q = 0; q < 4; ++q){
          p[q][0] += __shfl_xor(p[q][0], m, 64);
          p[q][1] += __shfl_xor(p[q][1], m, 64);
          p[q][2] += __shfl_xor(p[q][2], m, 64);
        }
      if (l16 < 3){
        const float bo1v = (l16 == 0) ? bo1_0 : ((l16 == 1) ? bo1_1 : bo1_2);
        #pragma unroll
        for (int q = 0; q < 4; ++q){
          const float vv = (l16 == 0) ? p[q][0] : ((l16 == 1) ? p[q][1] : p[q][2]);
          out[((size_t)b*VV + half*HV + tb + kb*4 + q)*3 + l16] = fmaxf(vv + bo1v, 0.f);
        }
      }
    }
  }
}

extern "C" void kernel_launch(void* const* d_in, const int* in_sizes, int n_in,
                              void* d_out, int out_size, void* d_ws, size_t ws_size,
                              hipStream_t stream) {
  const float* x      = (const float*)d_in[0];
  const float* bn0_g  = (const float*)d_in[1];
  const float* bn0_b  = (const float*)d_in[2];
  const float* bn0_m  = (const float*)d_in[3];
  const float* bn0_v  = (const float*)d_in[4];
  const float* W_in   = (const float*)d_in[5];
  const float* b_in   = (const float*)d_in[6];
  const float* W_flr  = (const float*)d_in[7];
  const float* b_flr  = (const float*)d_in[8];
  const float* W_s    = (const float*)d_in[9];
  const float* b_s    = (const float*)d_in[10];
  const float* W_out  = (const float*)d_in[11];
  const float* b_out  = (const float*)d_in[12];
  const float* bn_g   = (const float*)d_in[13];
  const float* bn_b   = (const float*)d_in[14];
  const float* bn_m   = (const float*)d_in[15];
  const float* bn_v   = (const float*)d_in[16];
  const float* W_o0   = (const float*)d_in[17];
  const float* b_o0   = (const float*)d_in[18];
  const float* W_o1   = (const float*)d_in[19];
  const float* b_o1   = (const float*)d_in[20];

  hipMemsetAsync(d_ws, 0, BB * sizeof(int), stream);

  garnet_fused<<<dim3(BB * 2), dim3(TPB), 0, stream>>>(
      x, bn0_g, bn0_b, bn0_m, bn0_v, W_in, b_in,
      W_flr, b_flr, W_s, b_s, W_out, b_out,
      bn_g, bn_b, bn_m, bn_v, W_o0, b_o0, W_o1, b_o1,
      (int*)d_ws, (float*)d_ws, (float*)d_out);
}

// Round 15
// 164.081 us; speedup vs baseline: 3.8713x; 1.1224x over previous
//
#include <hip/hip_runtime.h>
#include <math.h>

#define NBLK  11
#define NAGG  4
#define NFILT 32
#define NPROP 20
#define BB    128
#define VV    1024
#define HV    512
#define FIN   10
#define TPB   512
#define BN_EPS 1e-3f
#define SHS   40   // sH row stride in halves: 80 B = 16B-aligned

// d_ws layout (floats): [0..127] int flags; mean; agg; then OPTIONAL f16 frag
// table (only if ws_size permits -- checked host-side; r14's tripwire was an
// OOB d_ws write corrupting a neighbor allocation).
#define WSF_MEAN 128
#define WSF_AGG  (WSF_MEAN + BB*2*FIN)                  // 2688
#define WSF_FRAG (WSF_AGG + (BB*2*2) * NAGG * 48)      // 100992 floats = 404 KB (r13-proven)
#define NFRAG    (NBLK*7*64*8)                          // 39424 f16 = 79 KB

typedef _Float16 f16;
typedef f16   f16x8 __attribute__((ext_vector_type(8)));
typedef float f32x4 __attribute__((ext_vector_type(4)));

__device__ __forceinline__ f32x4 MFMA(f16x8 a, f16x8 b, f32x4 c){
  return __builtin_amdgcn_mfma_f32_16x16x32_f16(a, b, c, 0, 0, 0);
}

__device__ __forceinline__ float fast_tanh(float x){
  float a = fabsf(x);
  float e = __expf(-2.0f * a);
  float r = (1.0f - e) / (1.0f + e);
  return copysignf(r, x);
}

// Pairwise event sync, RELAXED (no wbl2 flush) — proven r13.
__device__ __forceinline__ void pair_sync(int* flag, int target){
  __syncthreads();
  if (threadIdx.x == 0){
    asm volatile("s_waitcnt vmcnt(0)" ::: "memory");
    __hip_atomic_fetch_add(flag, 1, __ATOMIC_RELAXED, __HIP_MEMORY_SCOPE_AGENT);
    while (__hip_atomic_load(flag, __ATOMIC_RELAXED, __HIP_MEMORY_SCOPE_AGENT) < target)
      __builtin_amdgcn_s_sleep(2);
  }
  __syncthreads();
}

// prep: build f16 B-fragment table (79 KB) once per launch.
// frag[((l*7+set)*64+lane)*8 + j]:
//   set 0,1 : stage1 [Wf|Ws|0] cols s*16+l16, k=kb*8+j
//   set 2,3 : stage3 WoH (Wo rows 0..31)
//   set 4,5,6: phaseC W_o0 slice
extern "C" __global__ void garnet_prep(
    const float* __restrict__ W_flr, const float* __restrict__ W_s,
    const float* __restrict__ W_out, const float* __restrict__ W_o0,
    f16* __restrict__ frag)
{
  const int idx = blockIdx.x * blockDim.x + threadIdx.x;
  if (idx >= NFRAG) return;
  const int j    = idx & 7;
  const int lane = (idx >> 3) & 63;
  const int rest = idx >> 9;
  const int set  = rest % 7;
  const int l    = rest / 7;
  const int l16  = lane & 15, kb = lane >> 4, k = kb*8 + j;
  float val = 0.f;
  if (set < 2){
    const int n = set*16 + l16;
    if (set == 0) val = W_flr[l*NFILT*NPROP + k*NPROP + n];
    else          val = (n < 20) ? W_flr[l*NFILT*NPROP + k*NPROP + n]
                       : (n < 24 ? W_s[l*NFILT*NAGG + k*NAGG + (n-20)] : 0.f);
  } else if (set < 4){
    const int s = set - 2;
    val = W_out[l*228*NFILT + k*NFILT + s*16 + l16];
  } else {
    const int s = set - 4;
    val = W_o0[((size_t)l*NFILT + k)*48 + s*16 + l16];
  }
  frag[idx] = (f16)val;
}

// r13 structure: 256 WGs, 2/event, 1 WG/CU; TPB=512 -> 128 VGPR.
// frag != nullptr -> vectorized fragment loads; else inline build (r13 path).
// MFMA 16x16x32 frags (m89-verified): A[row=lane&15][k=8*(lane>>4)+j],
// B[k][col=lane&15], C[row=4*(lane>>4)+q][col=lane&15].
extern "C" __global__ __launch_bounds__(TPB)
void garnet_fused(
    const float* __restrict__ x,
    const float* __restrict__ bn0_g, const float* __restrict__ bn0_b,
    const float* __restrict__ bn0_m, const float* __restrict__ bn0_v,
    const float* __restrict__ W_in,  const float* __restrict__ b_in,
    const float* __restrict__ W_flr, const float* __restrict__ b_flr,
    const float* __restrict__ W_s,   const float* __restrict__ b_s,
    const float* __restrict__ W_out, const float* __restrict__ b_out,
    const float* __restrict__ bn_g,  const float* __restrict__ bn_b,
    const float* __restrict__ bn_m,  const float* __restrict__ bn_v,
    const float* __restrict__ W_o0,  const float* __restrict__ b_o0,
    const float* __restrict__ W_o1,  const float* __restrict__ b_o1,
    int* __restrict__ wsFlag, float* __restrict__ wsF,
    const f16* __restrict__ frag,
    float* __restrict__ out)
{
  const int wg   = blockIdx.x;
  const int b    = wg & (BB - 1);
  const int half = wg >> 7;
  const int t    = threadIdx.x;
  const int lane = t & 63;
  const int wave = t >> 6;
  const int v    = half * HV + t;
  const int l16  = lane & 15;
  const int kb   = lane >> 4;

  __shared__ float sFeat[HV * 25];                 // 50 KB
  __shared__ __align__(16) f16 sHhi[HV * SHS];     // 40 KB
  __shared__ __align__(16) f16 sHlo[HV * SHS];     // 40 KB
  __shared__ f16   sMh[4 * 32];
  __shared__ float sAgg[NAGG][48];
  __shared__ float sRed[8][FIN];
  __shared__ float sMean[FIN];

  int* flag = wsFlag + b;

  // ---------------- phase 0: mean over V (cross-half) + input dense ----------------
  {
    float h[NFILT];
    float xv[FIN];
    const float* xp = x + ((size_t)b * VV + v) * FIN;
    #pragma unroll
    for (int c = 0; c < FIN; ++c) xv[c] = xp[c];

    float ps[FIN];
    #pragma unroll
    for (int c = 0; c < FIN; ++c) ps[c] = xv[c];
    #pragma unroll
    for (int m = 32; m > 0; m >>= 1){
      #pragma unroll
      for (int c = 0; c < FIN; ++c) ps[c] += __shfl_xor(ps[c], m, 64);
    }
    if (lane == 0){
      #pragma unroll
      for (int c = 0; c < FIN; ++c) sRed[wave][c] = ps[c];
    }
    __syncthreads();
    if (t < FIN){
      float s = 0.f;
      #pragma unroll
      for (int wv = 0; wv < 8; ++wv) s += sRed[wv][t];
      sRed[0][t] = s;
      __hip_atomic_store(&wsF[WSF_MEAN + (b*2 + half)*FIN + t], s,
                         __ATOMIC_RELAXED, __HIP_MEMORY_SCOPE_AGENT);
    }
    pair_sync(flag, 2);
    if (t < FIN){
      float theirs = __hip_atomic_load(&wsF[WSF_MEAN + (b*2 + (half^1))*FIN + t],
                                       __ATOMIC_RELAXED, __HIP_MEMORY_SCOPE_AGENT);
      sMean[t] = (sRed[0][t] + theirs) * (1.0f / VV);
    }
    __syncthreads();

    float o[NFILT];
    #pragma unroll
    for (int j = 0; j < NFILT; ++j) o[j] = b_in[j];
    #pragma unroll
    for (int c = 0; c < FIN; ++c){
      const float zx = (xv[c]    - bn0_m[c])     * (bn0_g[c]     * rsqrtf(bn0_v[c]     + BN_EPS)) + bn0_b[c];
      const float zm = (sMean[c] - bn0_m[FIN+c]) * (bn0_g[FIN+c] * rsqrtf(bn0_v[FIN+c] + BN_EPS)) + bn0_b[FIN+c];
      #pragma unroll
      for (int j = 0; j < NFILT; ++j)
        o[j] += zx * W_in[c*NFILT + j] + zm * W_in[(FIN+c)*NFILT + j];
    }
    #pragma unroll
    for (int j = 0; j < NFILT; ++j) h[j] = fast_tanh(o[j]);

    #pragma unroll
    for (int c = 0; c < 4; ++c){
      f16x8 hh, hl;
      #pragma unroll
      for (int j = 0; j < 8; ++j){
        const float hv = h[c*8 + j];
        const f16 a = (f16)hv;
        hh[j] = a;
        hl[j] = (f16)(hv - (float)a);
      }
      *(f16x8*)&sHhi[t*SHS + c*8] = hh;
      *(f16x8*)&sHlo[t*SHS + c*8] = hl;
    }
  }
  __syncthreads();

  f32x4 acc[4][3];
  #pragma unroll
  for (int s = 0; s < 3; ++s){
    const float a0 = b_o0[s*16 + l16];
    #pragma unroll
    for (int i = 0; i < 4; ++i) acc[i][s] = (f32x4){a0, a0, a0, a0};
  }

  for (int l = 0; l < NBLK; ++l){
    const float* Wf = W_flr + l * NFILT * NPROP;
    const float* bf = b_flr + l * NPROP;
    const float* Ws = W_s   + l * NFILT * NAGG;
    const float* bs = b_s   + l * NAGG;
    const float* Wo = W_out + l * 228 * NFILT;
    const float* bo = b_out + l * NFILT;
    const float* g_ = bn_g  + l * NFILT;
    const float* be = bn_b  + l * NFILT;
    const float* bm = bn_m  + l * NFILT;
    const float* bv = bn_v  + l * NFILT;
    const f16*  fl  = frag + (size_t)l * 7 * 64 * 8;

    // ---- stage 1 (MFMA): feat = h @ [Wf|Ws], w = exp(-|d|) -> sFeat fp32 ----
    {
      f16x8 b1f0, b1f1;
      if (frag){
        b1f0 = *(const f16x8*)&fl[(size_t)(0*64 + lane)*8];
        b1f1 = *(const f16x8*)&fl[(size_t)(1*64 + lane)*8];
      } else {
        #pragma unroll
        for (int j = 0; j < 8; ++j){
          const int k = kb*8 + j;
          b1f0[j] = (f16)Wf[k*NPROP + l16];
          const int n = 16 + l16;
          b1f1[j] = (f16)((n < 20) ? Wf[k*NPROP + n] : (n < 24 ? Ws[k*NAGG + (n-20)] : 0.f));
        }
      }
      const float bias0 = bf[l16];
      const int  c1 = 16 + l16;
      const float bias1 = (c1 < 20) ? bf[c1] : (c1 < 24 ? bs[c1-20] : 0.f);

      #pragma unroll
      for (int i = 0; i < 4; ++i){
        const int tb = wave*64 + i*16;
        const f16x8 ahi = *(const f16x8*)&sHhi[(tb + l16)*SHS + kb*8];
        const f16x8 alo = *(const f16x8*)&sHlo[(tb + l16)*SHS + kb*8];
        f32x4 c0 = (f32x4){bias0, bias0, bias0, bias0};
        c0 = MFMA(ahi, b1f0, c0);
        c0 = MFMA(alo, b1f0, c0);
        #pragma unroll
        for (int q = 0; q < 4; ++q)
          sFeat[(tb + kb*4 + q)*25 + l16] = c0[q];
        f32x4 c1v = (f32x4){bias1, bias1, bias1, bias1};
        c1v = MFMA(ahi, b1f1, c1v);
        c1v = MFMA(alo, b1f1, c1v);
        if (l16 < 4){
          #pragma unroll
          for (int q = 0; q < 4; ++q)
            sFeat[(tb + kb*4 + q)*25 + 16 + l16] = c1v[q];
        } else if (l16 < 8){
          #pragma unroll
          for (int q = 0; q < 4; ++q)
            sFeat[(tb + kb*4 + q)*25 + 16 + l16] = __expf(-fabsf(c1v[q]));
        }
      }
    }
    __syncthreads();

    // ---- stage 2: partial max/sum over 512 rows; wave owns cols 3w..3w+2 ----
    {
      const int w3 = wave * 3;
      float psum[NAGG][3], pmax[NAGG][3];
      #pragma unroll
      for (int a = 0; a < NAGG; ++a)
        #pragma unroll
        for (int c = 0; c < 3; ++c){ psum[a][c] = 0.f; pmax[a][c] = -INFINITY; }
      for (int i = 0; i < 8; ++i){
        const int row = i * 64 + lane;
        float fc[3], wa[NAGG];
        #pragma unroll
        for (int c = 0; c < 3; ++c) fc[c] = sFeat[row*25 + w3 + c];
        #pragma unroll
        for (int a = 0; a < NAGG; ++a) wa[a] = sFeat[row*25 + NPROP + a];
        #pragma unroll
        for (int a = 0; a < NAGG; ++a)
          #pragma unroll
          for (int c = 0; c < 3; ++c){
            const float p = wa[a] * fc[c];
            psum[a][c] += p;
            pmax[a][c]  = fmaxf(pmax[a][c], p);
          }
      }
      #pragma unroll
      for (int m = 32; m > 0; m >>= 1){
        #pragma unroll
        for (int a = 0; a < NAGG; ++a)
          #pragma unroll
          for (int c = 0; c < 3; ++c){
            psum[a][c] += __shfl_xor(psum[a][c], m, 64);
            pmax[a][c]  = fmaxf(pmax[a][c], __shfl_xor(pmax[a][c], m, 64));
          }
      }
      if (lane == 0){
        float* gp = wsF + WSF_AGG + (((size_t)(b*2 + (l&1))*2 + half) * NAGG * 48);
        #pragma unroll
        for (int a = 0; a < NAGG; ++a)
          #pragma unroll
          for (int c = 0; c < 3; ++c){
            sAgg[a][w3 + c]      = pmax[a][c];
            sAgg[a][24 + w3 + c] = psum[a][c];
            __hip_atomic_store(&gp[a*48 + w3 + c],      pmax[a][c], __ATOMIC_RELAXED, __HIP_MEMORY_SCOPE_AGENT);
            __hip_atomic_store(&gp[a*48 + 24 + w3 + c], psum[a][c], __ATOMIC_RELAXED, __HIP_MEMORY_SCOPE_AGENT);
          }
      }
    }
    pair_sync(flag, 2*l + 4);

    if (t < 192){
      const int a = t / 48, c = t - a * 48;
      const float* pp = wsF + WSF_AGG + (((size_t)(b*2 + (l&1))*2 + (half^1)) * NAGG * 48);
      const float mine   = sAgg[a][c];
      const float theirs = __hip_atomic_load(&pp[a*48 + c], __ATOMIC_RELAXED, __HIP_MEMORY_SCOPE_AGENT);
      sAgg[a][c] = (c < 24) ? fmaxf(mine, theirs) : (mine + theirs) * (1.0f / VV);
    }
    __syncthreads();

    // ---- M'[a][j] -> fp16 (r13 form: scalar Wo loads) ----
    if (t < 128){
      const int a = t >> 5, j = t & 31;
      float m = Wo[(224 + a) * NFILT + j];
      #pragma unroll 8
      for (int c = 0; c < 48; ++c) m += sAgg[a][c] * Wo[(32 + a*48 + c) * NFILT + j];
      sMh[a*32 + j] = (f16)m;
    }
    __syncthreads();

    // ---- stage 3 (MFMA): o = h@WoH + w@M' + bo; h_new = bn(tanh(o)) -> sH ----
    {
      f16x8 b2f0, b2f1;
      if (frag){
        b2f0 = *(const f16x8*)&fl[(size_t)(2*64 + lane)*8];
        b2f1 = *(const f16x8*)&fl[(size_t)(3*64 + lane)*8];
      } else {
        #pragma unroll
        for (int j = 0; j < 8; ++j){
          const int k = kb*8 + j;
          b2f0[j] = (f16)Wo[k*NFILT + l16];
          b2f1[j] = (f16)Wo[k*NFILT + 16 + l16];
        }
      }
      f16x8 bmf[2];
      #pragma unroll
      for (int s = 0; s < 2; ++s)
        #pragma unroll
        for (int j = 0; j < 8; ++j)
          bmf[s][j] = (kb == 0 && j < 4) ? sMh[j*32 + s*16 + l16] : (f16)0.f;

      float boc[2], bmc[2], scc[2], bec[2];
      #pragma unroll
      for (int s = 0; s < 2; ++s){
        const int cc = s*16 + l16;
        boc[s] = bo[cc];
        bmc[s] = bm[cc];
        scc[s] = g_[cc] * rsqrtf(bv[cc] + BN_EPS);
        bec[s] = be[cc];
      }

      #pragma unroll
      for (int i = 0; i < 4; ++i){
        const int tb = wave*64 + i*16;
        const f16x8 ahi = *(const f16x8*)&sHhi[(tb + l16)*SHS + kb*8];
        const f16x8 alo = *(const f16x8*)&sHlo[(tb + l16)*SHS + kb*8];
        f16x8 wa;
        #pragma unroll
        for (int j = 0; j < 8; ++j) wa[j] = (f16)0.f;
        {
          const float w0 = sFeat[(tb + l16)*25 + 20];
          const float w1 = sFeat[(tb + l16)*25 + 21];
          const float w2 = sFeat[(tb + l16)*25 + 22];
          const float w3v = sFeat[(tb + l16)*25 + 23];
          if (kb == 0){ wa[0]=(f16)w0; wa[1]=(f16)w1; wa[2]=(f16)w2; wa[3]=(f16)w3v; }
        }
        #pragma unroll
        for (int s = 0; s < 2; ++s){
          f32x4 o = (f32x4){0.f, 0.f, 0.f, 0.f};
          o = MFMA(ahi, (s ? b2f1 : b2f0), o);
          o = MFMA(alo, (s ? b2f1 : b2f0), o);
          o = MFMA(wa,  bmf[s], o);
          #pragma unroll
          for (int q = 0; q < 4; ++q){
            const float th = fast_tanh(o[q] + boc[s]);
            const float hn = (th - bmc[s]) * scc[s] + bec[s];
            const f16 hh = (f16)hn;
            const int idx = (tb + kb*4 + q)*SHS + s*16 + l16;
            sHhi[idx] = hh;
            sHlo[idx] = (f16)(hn - (float)hh);
          }
        }
      }
    }
    asm volatile("s_waitcnt lgkmcnt(0)" ::: "memory");

    // ---- phase C (MFMA): acc += h_new @ W_o0_slice ----
    {
      f16x8 b3f[3];
      if (frag){
        #pragma unroll
        for (int s = 0; s < 3; ++s)
          b3f[s] = *(const f16x8*)&fl[(size_t)((4 + s)*64 + lane)*8];
      } else {
        const float* Wo0l = W_o0 + (size_t)l * NFILT * 48;
        #pragma unroll
        for (int s = 0; s < 3; ++s)
          #pragma unroll
          for (int j = 0; j < 8; ++j)
            b3f[s][j] = (f16)Wo0l[(kb*8 + j)*48 + s*16 + l16];
      }
      #pragma unroll
      for (int i = 0; i < 4; ++i){
        const int tb = wave*64 + i*16;
        const f16x8 ahi = *(const f16x8*)&sHhi[(tb + l16)*SHS + kb*8];
        const f16x8 alo = *(const f16x8*)&sHlo[(tb + l16)*SHS + kb*8];
        #pragma unroll
        for (int s = 0; s < 3; ++s){
          acc[i][s] = MFMA(ahi, b3f[s], acc[i][s]);
          acc[i][s] = MFMA(alo, b3f[s], acc[i][s]);
        }
      }
    }
  }

  // ---------------- head: out = relu(relu(acc) @ W_o1 + b_o1) ----------------
  {
    float w1c[3][3];
    #pragma unroll
    for (int s = 0; s < 3; ++s)
      #pragma unroll
      for (int m = 0; m < 3; ++m) w1c[s][m] = W_o1[(s*16 + l16)*3 + m];
    const float bo1_0 = b_o1[0], bo1_1 = b_o1[1], bo1_2 = b_o1[2];

    #pragma unroll
    for (int i = 0; i < 4; ++i){
      const int tb = wave*64 + i*16;
      float p[4][3];
      #pragma unroll
      for (int q = 0; q < 4; ++q){ p[q][0]=0.f; p[q][1]=0.f; p[q][2]=0.f; }
      #pragma unroll
      for (int s = 0; s < 3; ++s)
        #pragma unroll
        for (int q = 0; q < 4; ++q){
          const float r_ = fmaxf(acc[i][s][q], 0.f);
          p[q][0] += r_ * w1c[s][0];
          p[q][1] += r_ * w1c[s][1];
          p[q][2] += r_ * w1c[s][2];
        }
      #pragma unroll
      for (int m = 1; m <= 8; m <<= 1)
        #pragma unroll
        for (int q = 0; q < 4; ++q){
          p[q][0] += __shfl_xor(p[q][0], m, 64);
          p[q][1] += __shfl_xor(p[q][1], m, 64);
          p[q][2] += __shfl_xor(p[q][2], m, 64);
        }
      if (l16 < 3){
        const float bo1v = (l16 == 0) ? bo1_0 : ((l16 == 1) ? bo1_1 : bo1_2);
        #pragma unroll
        for (int q = 0; q < 4; ++q){
          const float vv = (l16 == 0) ? p[q][0] : ((l16 == 1) ? p[q][1] : p[q][2]);
          out[((size_t)b*VV + half*HV + tb + kb*4 + q)*3 + l16] = fmaxf(vv + bo1v, 0.f);
        }
      }
    }
  }
}

extern "C" void kernel_launch(void* const* d_in, const int* in_sizes, int n_in,
                              void* d_out, int out_size, void* d_ws, size_t ws_size,
                              hipStream_t stream) {
  const float* x      = (const float*)d_in[0];
  const float* bn0_g  = (const float*)d_in[1];
  const float* bn0_b  = (const float*)d_in[2];
  const float* bn0_m  = (const float*)d_in[3];
  const float* bn0_v  = (const float*)d_in[4];
  const float* W_in   = (const float*)d_in[5];
  const float* b_in   = (const float*)d_in[6];
  const float* W_flr  = (const float*)d_in[7];
  const float* b_flr  = (const float*)d_in[8];
  const float* W_s    = (const float*)d_in[9];
  const float* b_s    = (const float*)d_in[10];
  const float* W_out  = (const float*)d_in[11];
  const float* b_out  = (const float*)d_in[12];
  const float* bn_g   = (const float*)d_in[13];
  const float* bn_b   = (const float*)d_in[14];
  const float* bn_m   = (const float*)d_in[15];
  const float* bn_v   = (const float*)d_in[16];
  const float* W_o0   = (const float*)d_in[17];
  const float* b_o0   = (const float*)d_in[18];
  const float* W_o1   = (const float*)d_in[19];
  const float* b_o1   = (const float*)d_in[20];

  float* wsF = (float*)d_ws;
  // frag table only if workspace is big enough (r14 lesson: never exceed ws_size)
  const size_t needed = (size_t)WSF_FRAG * 4 + (size_t)NFRAG * 2;
  _Float16* frag = (ws_size >= needed) ? (_Float16*)(wsF + WSF_FRAG) : nullptr;

  hipMemsetAsync(d_ws, 0, BB * sizeof(int), stream);

  if (frag)
    garnet_prep<<<dim3((NFRAG + 255) / 256), dim3(256), 0, stream>>>(
        W_flr, W_s, W_out, W_o0, frag);

  garnet_fused<<<dim3(BB * 2), dim3(TPB), 0, stream>>>(
      x, bn0_g, bn0_b, bn0_m, bn0_v, W_in, b_in,
      W_flr, b_flr, W_s, b_s, W_out, b_out,
      bn_g, bn_b, bn_m, bn_v, W_o0, b_o0, W_o1, b_o1,
      (int*)d_ws, wsF, frag, (float*)d_out);
}